// Round 10
// baseline (209.656 us; speedup 1.0000x reference)
//
#include <hip/hip_runtime.h>

#define B_ 8
#define C_ 256
#define HW_ 4096
#define E_ 32
#define K_ 8192
#define N_ 32768          // B*H*W
#define NSTAGE (K_ / 128)    // 64 stages: full codebook per block
#define KSEG 32              // codes per k_dwfinal block
#define PIX 128              // pixels per k_score block

#define DECAY_ 0.99f
#define OMD_   0.01f
#define EPS_   1e-5f
#define BETA_  0.25f

// ---- output layout (fp32 elements, concatenated in reference return order) ----
#define O_ZQ   0          // [B,E,H,W] 1048576
#define O_IDX  1048576    // [B,H,W]   32768
#define O_QL   1081344    // scalar    1
#define O_NEMB 1081345    // [K,E]     262144
#define O_NCS  1343489    // [K]       8192
#define O_NW   1351681    // [K,E]     262144

// ---- workspace layout (float offsets); high-water 1310992 floats = 5.2 MB ----
// eh/em PRE-SWIZZLED to MFMA-frag order: uint4 chunk (tile t, quad q, c15) at t*64+q*16+c15.
#define WS_EH   0u        // K*E bf16 hi   [0,       131072)
#define WS_EM   131072u   // K*E bf16 lo   [131072,  262144)
#define WS_Z    262144u   // N*E fp32 z    [262144, 1310720)
#define WS_PCS  1310720u  // 16 per-block partial sums of cs_in
#define WS_QP   1310736u  // 256 per-block qloss partials
// NO memset needed: every ws word consumed is written first by a prior kernel.

typedef float f32x4 __attribute__((ext_vector_type(4)));
typedef short s16x8 __attribute__((ext_vector_type(8)));
typedef unsigned long long u64;

__device__ __forceinline__ unsigned short f2bf(float f) {
    unsigned u = __float_as_uint(f);
    u = u + 0x7fffu + ((u >> 16) & 1u);
    return (unsigned short)(u >> 16);
}
__device__ __forceinline__ float bf2f(unsigned short h) {
    return __uint_as_float(((unsigned)h) << 16);
}
__device__ __forceinline__ unsigned ford(float f) {
    unsigned u = __float_as_uint(f);
    return (u & 0x80000000u) ? ~u : (u | 0x80000000u);
}
__device__ __forceinline__ int imax(int a, int b) { return a > b ? a : b; }
__device__ __forceinline__ int imin(int a, int b) { return a < b ? a : b; }

__device__ __forceinline__ void gload_lds16(const void* g, void* l) {
    __builtin_amdgcn_global_load_lds(
        (const __attribute__((address_space(1))) unsigned int*)g,
        (__attribute__((address_space(3))) unsigned int*)l, 16, 0, 0);
}

// ---------------- K0: fused {norm_split + cs-partials} || {z = x@WqT + bq}, 512 thr ----------------
// blocks [0,16): codebook normalize/split, 1 row/thread + cs partial.
// blocks [16,272): z for 128 pixels; 2 px x 4 e per thread; unroll 8 -> 16 x-loads in flight.
__global__ __launch_bounds__(512) void k_pre(const float* __restrict__ emb,
                                             const float* __restrict__ cs,
                                             uint4* __restrict__ eh16,
                                             uint4* __restrict__ em16,
                                             float* __restrict__ part_cs,
                                             const float* __restrict__ x,
                                             const float* __restrict__ Wq,
                                             const float* __restrict__ bq,
                                             float* __restrict__ zout) {
    __shared__ float wqt[C_ * E_];   // 32 KB (z branch)
    __shared__ float red8[8];        // (norm branch cs reduce)
    int tid = threadIdx.x;

    if (blockIdx.x < 16) {
        // ---- norm_split branch: one full row per thread ----
        int k = blockIdx.x * 512 + tid;            // 0..8191
        const float4* r = (const float4*)(emb + (size_t)k * E_);
        float v[E_];
        float ss = 0.f;
#pragma unroll
        for (int i = 0; i < 8; i++) {
            float4 t = r[i];
            v[i*4+0] = t.x; v[i*4+1] = t.y; v[i*4+2] = t.z; v[i*4+3] = t.w;
            ss += t.x*t.x + t.y*t.y + t.z*t.z + t.w*t.w;
        }
        float inv = 1.0f / fmaxf(sqrtf(ss), 1e-12f);
        unsigned short h1a[E_], h2a[E_];
#pragma unroll
        for (int e = 0; e < E_; e++) {
            float en = v[e] * inv;
            unsigned short h1 = f2bf(en);
            float r1 = en - bf2f(h1);
            h1a[e] = h1; h2a[e] = f2bf(r1);
        }
        int t = k >> 4, c15 = k & 15;
#pragma unroll
        for (int i = 0; i < 4; i++) {   // quad i = elements 8i..8i+7
            eh16[t * 64 + i * 16 + c15] = ((uint4*)h1a)[i];
            em16[t * 64 + i * 16 + c15] = ((uint4*)h2a)[i];
        }

        // per-block partial of sum(cs_in): rows [blockIdx*512, +512)
        float cv = cs[blockIdx.x * 512 + tid];
#pragma unroll
        for (int off = 32; off > 0; off >>= 1) cv += __shfl_down(cv, off);
        int lane = tid & 63, wid = tid >> 6;
        if (lane == 0) red8[wid] = cv;
        __syncthreads();
        if (tid == 0) {
            float s = 0.f;
#pragma unroll
            for (int i = 0; i < 8; i++) s += red8[i];
            part_cs[blockIdx.x] = s;
        }
        return;
    }

    // ---- z branch: 128 pixels; thread owns px (lp, lp+64) x 4 e's ----
    int zb = blockIdx.x - 16;
#pragma unroll
    for (int i = 0; i < 16; i++) {
        int g = i * 512 + tid;        // g = e*256 + c  (Wq is [E,C])
        int e = g >> 8;
        int c = g & 255;
        wqt[c * E_ + e] = Wq[g];
    }
    __syncthreads();
    int lp = tid & 63, eg = tid >> 6;   // eg 0..7, 4 e's each
    int n0 = zb * 128 + lp;             // px A; px B = n0+64 (same image: 128 | 4096)
    int b  = n0 >> 12, hw = n0 & (HW_ - 1);
    const float* xp = x + (size_t)b * C_ * HW_ + hw;
    float a[8];
#pragma unroll
    for (int j = 0; j < 8; j++) a[j] = 0.f;
#pragma unroll 8
    for (int c = 0; c < C_; c++) {
        float xa = xp[(size_t)c * HW_];
        float xb = xp[(size_t)c * HW_ + 64];
        float4 wv = *(const float4*)(wqt + c * E_ + eg * 4);   // wave-uniform broadcast
        a[0] += xa * wv.x; a[1] += xa * wv.y; a[2] += xa * wv.z; a[3] += xa * wv.w;
        a[4] += xb * wv.x; a[5] += xb * wv.y; a[6] += xb * wv.z; a[7] += xb * wv.w;
    }
    float bq0 = bq[eg*4+0], bq1v = bq[eg*4+1], bq2v = bq[eg*4+2], bq3 = bq[eg*4+3];
    *(float4*)(zout + (size_t)n0 * E_ + eg * 4) =
        make_float4(a[0]+bq0, a[1]+bq1v, a[2]+bq2v, a[3]+bq3);
    *(float4*)(zout + (size_t)(n0 + 64) * E_ + eg * 4) =
        make_float4(a[4]+bq0, a[5]+bq1v, a[6]+bq2v, a[7]+bq3);
}

// exact rescore of one candidate code against z[32] (zrow may be LDS)
__device__ __forceinline__ float rescore(const float* __restrict__ emb, int k,
                                         const float* zrow) {
    const float4* r = (const float4*)(emb + (size_t)k * E_);
    float4 v[8];
    float ss = 0.f;
#pragma unroll
    for (int i = 0; i < 8; i++) {
        v[i] = r[i];
        ss += v[i].x * v[i].x + v[i].y * v[i].y + v[i].z * v[i].z + v[i].w * v[i].w;
    }
    float inv = 1.0f / fmaxf(sqrtf(ss), 1e-12f);
    const float4* zp = (const float4*)zrow;
    float sx = 0.f, sy = 0.f, sz = 0.f, sw = 0.f;
#pragma unroll
    for (int i = 0; i < 8; i++) {
        float4 e4 = make_float4(v[i].x * inv, v[i].y * inv, v[i].z * inv, v[i].w * inv);
        float4 zr = zp[i];
        sx += zr.x * e4.x; sy += zr.y * e4.y;
        sz += zr.z * e4.z; sw += zr.w * e4.w;
    }
    return (sx + sy) + (sz + sw);
}

// ---------------- K1: FUSED MFMA score (full codebook) + top-2 + rescore + scatter ----------------
// grid N/128 = 256 blocks (1/CU), 512 thr (8 waves), 128 pixels, ALL 8192 codes in 64 stages.
// Inner per-stage loop identical to the measured 60 µs kernel. Epilogue replaces k_scatter:
// in-LDS z rows, exact rescore of global top-2, idx + coalesced zq + qloss partial.
// NO min-waves clause (round-3: forcing occupancy spills; WRITE_SIZE is the tripwire).
__global__ __launch_bounds__(512) void k_score_fused(const float* __restrict__ zws,
                                                     const char* __restrict__ ehb,
                                                     const char* __restrict__ emb_b,
                                                     const float* __restrict__ emb,
                                                     float* __restrict__ out_zq,
                                                     float* __restrict__ out_idx,
                                                     float* __restrict__ qpart) {
    __shared__ __align__(16) char smem[32768];   // B staging dbuf
    __shared__ float zbuf[PIX * E_];             // 16 KB z rows
    __shared__ int2  t2[PIX];                    // per-pixel packed top-2
    __shared__ float red8[8];

    int tid  = threadIdx.x;
    int lane = tid & 63;
    int w    = tid >> 6;          // 0..7

    // ---- A fragments from cached z (also fill zbuf): z * 2^27 (exact), 2-way bf16 split.
    //      A[m=lane&15][k=(lane>>4)*8+j]; 512 threads cover 128 px x 4 e-octets exactly. ----
    s16x8 a1, a2;
    {
        int ploc = w * 16 + (lane & 15);          // 0..127
        int n0   = blockIdx.x * PIX + ploc;
        int e0   = (lane >> 4) * 8;
        const float4* zp = (const float4*)(zws + (size_t)n0 * E_ + e0);
        float4 z0 = zp[0], z1 = zp[1];
        *(float4*)(zbuf + ploc * E_ + e0)     = z0;
        *(float4*)(zbuf + ploc * E_ + e0 + 4) = z1;
        float zz[8] = {z0.x, z0.y, z0.z, z0.w, z1.x, z1.y, z1.z, z1.w};
#pragma unroll
        for (int j = 0; j < 8; j++) {
            float zv = zz[j] * 134217728.0f;  // 2^27
            unsigned short h1 = f2bf(zv);
            float r1 = zv - bf2f(h1);
            a1[j] = (short)h1; a2[j] = (short)f2bf(r1);
        }
    }

    // staging sources (pre-swizzled planes are stage-linear); 512 thr x 2 = 1024 chunks
    const char* srcp[2];
#pragma unroll
    for (int i = 0; i < 2; i++) {
        int d = i * 512 + tid;
        int pl = d >> 9, dd = d & 511;
        srcp[i] = (pl ? emb_b : ehb) + dd * 16;
    }

    // prologue: stage 0 -> buf0
#pragma unroll
    for (int i = 0; i < 2; i++)
        gload_lds16(srcp[i], smem + (i * 512 + tid) * 16);
    __syncthreads();

    int rbase = 8191 - (lane & 15);
    int bq1[4], bq2[4];
#pragma unroll
    for (int j = 0; j < 4; j++) { bq1[j] = (int)0x80000000; bq2[j] = (int)0x80000000; }
    f32x4 zero4 = {0.f, 0.f, 0.f, 0.f};

    for (int st = 0; st < NSTAGE; st++) {
        if (st + 1 < NSTAGE) {
            char* dst = smem + ((st + 1) & 1) * 16384;
#pragma unroll
            for (int i = 0; i < 2; i++)
                gload_lds16(srcp[i] + (size_t)(st + 1) * 8192, dst + (i * 512 + tid) * 16);
        }
        const char* cur = smem + (st & 1) * 16384;
        int rst = rbase - st * 128;

#pragma unroll
        for (int g = 0; g < 2; g++) {
            int ct = g * 4;
            s16x8 b1[4], b2[4];
#pragma unroll
            for (int q = 0; q < 4; q++) {
                b1[q] = ((const s16x8*)(cur +        (ct + q) * 1024))[lane];
                b2[q] = ((const s16x8*)(cur + 8192 + (ct + q) * 1024))[lane];
            }
            f32x4 acc[4];
#pragma unroll
            for (int q = 0; q < 4; q++)
                acc[q] = __builtin_amdgcn_mfma_f32_16x16x32_bf16(a1, b1[q], zero4, 0, 0, 0);
#pragma unroll
            for (int q = 0; q < 4; q++)
                acc[q] = __builtin_amdgcn_mfma_f32_16x16x32_bf16(a1, b2[q], acc[q], 0, 0, 0);
#pragma unroll
            for (int q = 0; q < 4; q++)
                acc[q] = __builtin_amdgcn_mfma_f32_16x16x32_bf16(a2, b1[q], acc[q], 0, 0, 0);
            int r0 = rst - ct * 16;
            // tournament over 4 tiles; only the group winner enters the running top-2.
            // (safe: a dropped group loser matters only on a packed-key quantization
            //  tie — P ~ 1e-4/run — and the exact rescore of top-2 covers ties.)
#pragma unroll
            for (int j = 0; j < 4; j++) {
                int v0 = ((int)acc[0][j] & (int)0xFFFFE000) | r0;
                int v1 = ((int)acc[1][j] & (int)0xFFFFE000) | (r0 - 16);
                int v2 = ((int)acc[2][j] & (int)0xFFFFE000) | (r0 - 32);
                int v3 = ((int)acc[3][j] & (int)0xFFFFE000) | (r0 - 48);
                int hi = imax(imax(v0, v1), imax(v2, v3));
                int m  = imin(bq1[j], hi);
                bq1[j] = imax(bq1[j], hi);
                bq2[j] = imax(bq2[j], m);
            }
        }
        __syncthreads();
    }

    // butterfly top-2 merge across 16-lane code groups -> per-pixel global top-2
#pragma unroll
    for (int off = 1; off < 16; off <<= 1) {
#pragma unroll
        for (int j = 0; j < 4; j++) {
            int o1 = __shfl_xor(bq1[j], off, 64);
            int o2 = __shfl_xor(bq2[j], off, 64);
            int m  = imin(bq1[j], o1);
            bq1[j] = imax(bq1[j], o1);
            bq2[j] = imax(imax(bq2[j], o2), m);
        }
    }
    if ((lane & 15) == 0) {
        int rowb = w * 16 + (lane >> 4) * 4;     // block-local pixel
#pragma unroll
        for (int j = 0; j < 4; j++)
            t2[rowb + j] = make_int2(bq1[j], bq2[j]);
    }
    __syncthreads();

    // ---- epilogue A: exact rescore of top-2, 4 thr/px (lanes 2,3 duplicate 0,1) ----
    {
        int p = tid >> 2, c4 = tid & 3;
        int2 c2 = t2[p];
        int raw = (c4 & 1) ? c2.y : c2.x;
        int k = 8191 - (raw & 0x1fff);
        k = k < 0 ? 0 : (k > K_ - 1 ? K_ - 1 : k);
        float s = rescore(emb, k, zbuf + p * E_);
        u64 pkd = ((u64)ford(s) << 32) | (unsigned)(K_ - 1 - k);  // ties -> lowest idx
        u64 o = __shfl_xor(pkd, 1, 64); pkd = pkd > o ? pkd : o;
        o = __shfl_xor(pkd, 2, 64);     pkd = pkd > o ? pkd : o;
        if (c4 == 0) {
            int bi = K_ - 1 - (int)(unsigned)(pkd & 0xffffffffu);
            ((int*)t2)[p * 2] = bi;                      // reuse t2.x as idx store
            out_idx[blockIdx.x * PIX + p] = (float)bi;
        }
    }
    __syncthreads();

    // ---- epilogue B: gather + coalesced zq write + qloss partial ----
    {
        int px = tid & 127, eg = tid >> 7;       // eg 0..3, 8 e's each
        int n  = blockIdx.x * PIX + px;          // 128 | 4096: no image crossing
        int b  = n >> 12, hw = n & (HW_ - 1);
        int idx = ((int*)t2)[px * 2];
        const float* er = emb + (size_t)idx * E_ + eg * 8;
        float* o = out_zq + (size_t)b * E_ * HW_ + (size_t)(eg * 8) * HW_ + hw;

        float sq = 0.f;
#pragma unroll
        for (int j = 0; j < 8; j++) {
            float zv = zbuf[px * E_ + eg * 8 + j];
            float qf = er[j];
            float d = qf - zv;
            sq += d * d;
            o[(size_t)j * HW_] = qf;
        }
#pragma unroll
        for (int off = 32; off > 0; off >>= 1) sq += __shfl_down(sq, off);
        if (lane == 0) red8[w] = sq;
        __syncthreads();
        if (tid == 0) {
            float s = 0.f;
#pragma unroll
            for (int i = 0; i < 8; i++) s += red8[i];
            qpart[blockIdx.x] = s;
        }
    }
}

// ---------------- K2: segment-sum + full EMA/division/qloss epilogue ----------------
// grid K/KSEG = 256 blocks; block owns codes [kbase, kbase+KSEG).
// Tile-list compaction (verified): scan 8 px/thread coalesced, LDS match list,
// fully-parallel list processing (8 rows x 32 e in flight).
__global__ __launch_bounds__(256) void k_dwfinal(const float* __restrict__ zws,
                                                 const float* __restrict__ idxf,
                                                 const float* __restrict__ cs,
                                                 const float* __restrict__ ew,
                                                 const float* __restrict__ part_cs,
                                                 const float* __restrict__ qpart,
                                                 float* __restrict__ out_nw,
                                                 float* __restrict__ out_nemb,
                                                 float* __restrict__ out_ncs,
                                                 float* __restrict__ out_ql) {
    __shared__ float acc[KSEG * E_];   // 4 KB
    __shared__ int   cnt_s[KSEG];
    __shared__ int   plist[2048];      // worst-case one tile fully matching
    __shared__ int   lcnt;
    __shared__ float nsum_s;
    int tid = threadIdx.x;
    int kbase = blockIdx.x * KSEG;

#pragma unroll
    for (int i = 0; i < KSEG * E_ / 256; i++) acc[tid + i * 256] = 0.f;
    if (tid < KSEG) cnt_s[tid] = 0;
    if (tid == 0) lcnt = 0;
    __syncthreads();

    const float4* idx4 = (const float4*)idxf;
    for (int tile = 0; tile < N_ / 2048; ++tile) {   // 16 tiles
        int pbase = tile * 2048 + tid * 8;
        float4 f0 = idx4[tile * 512 + tid * 2];
        float4 f1 = idx4[tile * 512 + tid * 2 + 1];
        float fs[8] = {f0.x, f0.y, f0.z, f0.w, f1.x, f1.y, f1.z, f1.w};
#pragma unroll
        for (int s = 0; s < 8; s++) {
            unsigned d = (unsigned)((int)fs[s] - kbase);
            if (d < (unsigned)KSEG) {
                int pos = atomicAdd(&lcnt, 1);
                plist[pos] = ((pbase + s) << 5) | (int)d;
                atomicAdd(cnt_s + (int)d, 1);
            }
        }
        __syncthreads();
        int cnt = lcnt;
        int e = tid & 31;
        for (int m = tid >> 5; m < cnt; m += 8) {
            int pk = plist[m];
            int nn = pk >> 5;
            float zv = zws[(size_t)nn * E_ + e];        // 128B coalesced per match
            atomicAdd(acc + (pk & 31) * E_ + e, zv);    // banks 0..31, conflict-free
        }
        __syncthreads();
        if (tid == 0) lcnt = 0;
        __syncthreads();
    }

    // nsum = DECAY*sum(cs_in) + OMD*N   (sum(counts) == N exactly)
    if (tid < 64) {                      // whole wave 0 active: shfl sources valid
        float s = (tid < 16) ? part_cs[tid] : 0.f;
        s += __shfl_down(s, 8);
        s += __shfl_down(s, 4);
        s += __shfl_down(s, 2);
        s += __shfl_down(s, 1);
        if (tid == 0) nsum_s = DECAY_ * s + OMD_ * (float)N_;
    }
    __syncthreads();
    float nsum = nsum_s;

#pragma unroll
    for (int i = 0; i < 4; i++) {
        int local = tid + i * 256;        // 0..1023
        int kl = local >> 5, c = local & 31;
        int k = kbase + kl;
        float v = DECAY_ * ew[(size_t)k * E_ + c] + OMD_ * acc[local];
        out_nw[(size_t)k * E_ + c] = v;
        float csk = DECAY_ * cs[k] + OMD_ * (float)cnt_s[kl];
        float denom = (csk + EPS_) / (nsum + (float)K_ * EPS_) * nsum;
        out_nemb[(size_t)k * E_ + c] = v / denom;
        if (c == 0) out_ncs[k] = csk;
    }

    if (blockIdx.x == 0 && tid < 64) {
        float s = 0.f;
#pragma unroll
        for (int i = 0; i < 4; i++) s += qpart[tid + i * 64];   // 256 partials
#pragma unroll
        for (int off = 32; off > 0; off >>= 1) s += __shfl_down(s, off);
        if (tid == 0) out_ql[0] = BETA_ * s / (float)(B_ * E_ * HW_);
    }
}

extern "C" void kernel_launch(void* const* d_in, const int* in_sizes, int n_in,
                              void* d_out, int out_size, void* d_ws, size_t ws_size,
                              hipStream_t stream) {
    const float* x   = (const float*)d_in[0];
    const float* Wq  = (const float*)d_in[1];
    const float* bq  = (const float*)d_in[2];
    const float* emb = (const float*)d_in[3];
    const float* cs  = (const float*)d_in[4];
    const float* ew  = (const float*)d_in[5];
    float* out = (float*)d_out;
    float* ws  = (float*)d_ws;

    // 3 dispatches total; no memset (all ws words written before read).
    k_pre<<<16 + N_ / 128, 512, 0, stream>>>(emb, cs,
        (uint4*)(ws + WS_EH), (uint4*)(ws + WS_EM), ws + WS_PCS,
        x, Wq, bq, ws + WS_Z);
    k_score_fused<<<N_ / PIX, 512, 0, stream>>>(ws + WS_Z,
        (const char*)(ws + WS_EH), (const char*)(ws + WS_EM), emb,
        out + O_ZQ, out + O_IDX, ws + WS_QP);
    k_dwfinal<<<K_ / KSEG, 256, 0, stream>>>(ws + WS_Z, out + O_IDX, cs, ew,
                                             ws + WS_PCS, ws + WS_QP,
                                             out + O_NW, out + O_NEMB,
                                             out + O_NCS, out + O_QL);
}

// Round 11
// 191.444 us; speedup vs baseline: 1.0951x; 1.0951x over previous
//
#include <hip/hip_runtime.h>

#define B_ 8
#define C_ 256
#define HW_ 4096
#define E_ 32
#define K_ 8192
#define N_ 32768          // B*H*W
#define NCHUNK 8
#define KC_ (K_ / NCHUNK) // 1024
#define NSTAGE (KC_ / 128)   // 8
#define KSEG 16              // codes per k_dwfinal block
#define PIX 128              // pixels per k_score block

#define DECAY_ 0.99f
#define OMD_   0.01f
#define EPS_   1e-5f
#define BETA_  0.25f

// ---- output layout (fp32 elements, concatenated in reference return order) ----
#define O_ZQ   0          // [B,E,H,W] 1048576
#define O_IDX  1048576    // [B,H,W]   32768
#define O_QL   1081344    // scalar    1
#define O_NEMB 1081345    // [K,E]     262144
#define O_NCS  1343489    // [K]       8192
#define O_NW   1351681    // [K,E]     262144

// ---- workspace layout (float offsets); high-water 1836048 floats = 7.3 MB ----
// eh/em PRE-SWIZZLED to MFMA-frag order: uint4 chunk (tile t, quad q, c15) at t*64+q*16+c15.
#define WS_EH   0u        // K*E bf16 hi   [0,       131072)
#define WS_EM   131072u   // K*E bf16 lo   [131072,  262144)
#define WS_Z    262144u   // N*E fp32 z    [262144, 1310720)
#define WS_PACK 1310720u  // 8 chunks x N int2 (top1,top2) [1310720, 1835008)
#define WS_PCS  1835008u  // 16 per-block partial sums of cs_in
#define WS_QP   1835024u  // 1024 per-block qloss partials
// NO memset needed: every ws word consumed is written first by a prior kernel.

typedef float f32x4 __attribute__((ext_vector_type(4)));
typedef short s16x8 __attribute__((ext_vector_type(8)));
typedef unsigned long long u64;

__device__ __forceinline__ unsigned short f2bf(float f) {
    unsigned u = __float_as_uint(f);
    u = u + 0x7fffu + ((u >> 16) & 1u);
    return (unsigned short)(u >> 16);
}
__device__ __forceinline__ float bf2f(unsigned short h) {
    return __uint_as_float(((unsigned)h) << 16);
}
__device__ __forceinline__ unsigned ford(float f) {
    unsigned u = __float_as_uint(f);
    return (u & 0x80000000u) ? ~u : (u | 0x80000000u);
}
__device__ __forceinline__ int imax(int a, int b) { return a > b ? a : b; }
__device__ __forceinline__ int imin(int a, int b) { return a < b ? a : b; }

__device__ __forceinline__ void gload_lds16(const void* g, void* l) {
    __builtin_amdgcn_global_load_lds(
        (const __attribute__((address_space(1))) unsigned int*)g,
        (__attribute__((address_space(3))) unsigned int*)l, 16, 0, 0);
}

// ---------------- K0: fused {norm_split + cs-partials} || {z = x@WqT + bq}, 512 thr ----------------
// blocks [0,16): codebook normalize/split, 1 row/thread + cs partial.
// blocks [16,528): z for 64 pixels each (1 px x 4 e per thread) -> 2+ blocks/CU.
__global__ __launch_bounds__(512) void k_pre(const float* __restrict__ emb,
                                             const float* __restrict__ cs,
                                             uint4* __restrict__ eh16,
                                             uint4* __restrict__ em16,
                                             float* __restrict__ part_cs,
                                             const float* __restrict__ x,
                                             const float* __restrict__ Wq,
                                             const float* __restrict__ bq,
                                             float* __restrict__ zout) {
    __shared__ float wqt[C_ * E_];   // 32 KB (z branch)
    __shared__ float red8[8];        // (norm branch cs reduce)
    int tid = threadIdx.x;

    if (blockIdx.x < 16) {
        // ---- norm_split branch: one full row per thread ----
        int k = blockIdx.x * 512 + tid;            // 0..8191
        const float4* r = (const float4*)(emb + (size_t)k * E_);
        float v[E_];
        float ss = 0.f;
#pragma unroll
        for (int i = 0; i < 8; i++) {
            float4 t = r[i];
            v[i*4+0] = t.x; v[i*4+1] = t.y; v[i*4+2] = t.z; v[i*4+3] = t.w;
            ss += t.x*t.x + t.y*t.y + t.z*t.z + t.w*t.w;
        }
        float inv = 1.0f / fmaxf(sqrtf(ss), 1e-12f);
        unsigned short h1a[E_], h2a[E_];
#pragma unroll
        for (int e = 0; e < E_; e++) {
            float en = v[e] * inv;
            unsigned short h1 = f2bf(en);
            float r1 = en - bf2f(h1);
            h1a[e] = h1; h2a[e] = f2bf(r1);
        }
        int t = k >> 4, c15 = k & 15;
#pragma unroll
        for (int i = 0; i < 4; i++) {   // quad i = elements 8i..8i+7
            eh16[t * 64 + i * 16 + c15] = ((uint4*)h1a)[i];
            em16[t * 64 + i * 16 + c15] = ((uint4*)h2a)[i];
        }

        // per-block partial of sum(cs_in): rows [blockIdx*512, +512)
        float cv = cs[blockIdx.x * 512 + tid];
#pragma unroll
        for (int off = 32; off > 0; off >>= 1) cv += __shfl_down(cv, off);
        int lane = tid & 63, wid = tid >> 6;
        if (lane == 0) red8[wid] = cv;
        __syncthreads();
        if (tid == 0) {
            float s = 0.f;
#pragma unroll
            for (int i = 0; i < 8; i++) s += red8[i];
            part_cs[blockIdx.x] = s;
        }
        return;
    }

    // ---- z branch: 64 pixels; thread owns 1 px x 4 e's ----
    int zb = blockIdx.x - 16;
#pragma unroll
    for (int i = 0; i < 16; i++) {
        int g = i * 512 + tid;        // g = e*256 + c  (Wq is [E,C])
        int e = g >> 8;
        int c = g & 255;
        wqt[c * E_ + e] = Wq[g];
    }
    __syncthreads();
    int lp = tid & 63, eg = tid >> 6;   // eg 0..7, 4 e's each
    int n0 = zb * 64 + lp;
    int b  = n0 >> 12, hw = n0 & (HW_ - 1);
    const float* xp = x + (size_t)b * C_ * HW_ + hw;
    float a0 = 0.f, a1 = 0.f, a2 = 0.f, a3 = 0.f;
#pragma unroll 8
    for (int c = 0; c < C_; c++) {
        float xv = xp[(size_t)c * HW_];
        float4 wv = *(const float4*)(wqt + c * E_ + eg * 4);   // wave-uniform broadcast
        a0 += xv * wv.x; a1 += xv * wv.y; a2 += xv * wv.z; a3 += xv * wv.w;
    }
    *(float4*)(zout + (size_t)n0 * E_ + eg * 4) =
        make_float4(a0 + bq[eg*4+0], a1 + bq[eg*4+1],
                    a2 + bq[eg*4+2], a3 + bq[eg*4+3]);
}

// ---------------- K1: MFMA score + int-packed per-pixel chunk-local top-2 ----------------
// grid (N/128, NCHUNK=8) = 2048 blocks, 512 thr (8 waves), 128 pixels, 1/8 codebook per block.
// 64 waves/CU oversubscribed (round-10 lesson: the scan is residency-bound).
// NO min-waves clause (round-3: forcing occupancy spills; WRITE_SIZE is the tripwire).
// LDS: [0,16384) buf0, [16384,32768) buf1 (stage: 8KB hi + 8KB lo).
__global__ __launch_bounds__(512) void k_score_mfma(const float* __restrict__ zws,
                                                    const char* __restrict__ ehb,
                                                    const char* __restrict__ emb_b,
                                                    int2* __restrict__ pk2) {
    __shared__ __align__(16) char smem[32768];

    int tid  = threadIdx.x;
    int lane = tid & 63;
    int w    = tid >> 6;          // 0..7
    int chunk = blockIdx.y;

    // ---- A fragments from cached z: z * 2^27 (exact), 2-way bf16 split.
    //      A[m=lane&15][k=(lane>>4)*8+j] ----
    s16x8 a1, a2;
    {
        int ploc = w * 16 + (lane & 15);          // 0..127
        int n0   = blockIdx.x * PIX + ploc;
        int e0   = (lane >> 4) * 8;
        const float4* zp = (const float4*)(zws + (size_t)n0 * E_ + e0);
        float4 z0 = zp[0], z1 = zp[1];
        float zz[8] = {z0.x, z0.y, z0.z, z0.w, z1.x, z1.y, z1.z, z1.w};
#pragma unroll
        for (int j = 0; j < 8; j++) {
            float zv = zz[j] * 134217728.0f;  // 2^27
            unsigned short h1 = f2bf(zv);
            float r1 = zv - bf2f(h1);
            a1[j] = (short)h1; a2[j] = (short)f2bf(r1);
        }
    }

    // staging sources (pre-swizzled planes are stage-linear); 512 thr x 2 = 1024 chunks
    const char* srcp[2];
#pragma unroll
    for (int i = 0; i < 2; i++) {
        int d = i * 512 + tid;
        int pl = d >> 9, dd = d & 511;
        srcp[i] = (pl ? emb_b : ehb) + (size_t)chunk * (KC_ * 64) + dd * 16;
    }

    // prologue: stage 0 -> buf0
#pragma unroll
    for (int i = 0; i < 2; i++)
        gload_lds16(srcp[i], smem + (i * 512 + tid) * 16);
    __syncthreads();

    int rbase = 8191 - chunk * KC_ - (lane & 15);
    int bq1[4], bq2[4];
#pragma unroll
    for (int j = 0; j < 4; j++) { bq1[j] = (int)0x80000000; bq2[j] = (int)0x80000000; }
    f32x4 zero4 = {0.f, 0.f, 0.f, 0.f};

    for (int st = 0; st < NSTAGE; st++) {
        if (st + 1 < NSTAGE) {
            char* dst = smem + ((st + 1) & 1) * 16384;
#pragma unroll
            for (int i = 0; i < 2; i++)
                gload_lds16(srcp[i] + (size_t)(st + 1) * 8192, dst + (i * 512 + tid) * 16);
        }
        const char* cur = smem + (st & 1) * 16384;
        int rst = rbase - st * 128;

#pragma unroll
        for (int g = 0; g < 2; g++) {
            int ct = g * 4;
            s16x8 b1[4], b2[4];
#pragma unroll
            for (int q = 0; q < 4; q++) {
                b1[q] = ((const s16x8*)(cur +        (ct + q) * 1024))[lane];
                b2[q] = ((const s16x8*)(cur + 8192 + (ct + q) * 1024))[lane];
            }
            f32x4 acc[4];
#pragma unroll
            for (int q = 0; q < 4; q++)
                acc[q] = __builtin_amdgcn_mfma_f32_16x16x32_bf16(a1, b1[q], zero4, 0, 0, 0);
#pragma unroll
            for (int q = 0; q < 4; q++)
                acc[q] = __builtin_amdgcn_mfma_f32_16x16x32_bf16(a1, b2[q], acc[q], 0, 0, 0);
#pragma unroll
            for (int q = 0; q < 4; q++)
                acc[q] = __builtin_amdgcn_mfma_f32_16x16x32_bf16(a2, b1[q], acc[q], 0, 0, 0);
            int r0 = rst - ct * 16;
            // tournament over 4 tiles; only the group winner enters the running top-2.
            // (safe: a dropped group loser matters only on a packed-key quantization
            //  tie — P ~ 1e-4/run — and the exact rescore of 16 candidates covers ties.)
#pragma unroll
            for (int j = 0; j < 4; j++) {
                int v0 = ((int)acc[0][j] & (int)0xFFFFE000) | r0;
                int v1 = ((int)acc[1][j] & (int)0xFFFFE000) | (r0 - 16);
                int v2 = ((int)acc[2][j] & (int)0xFFFFE000) | (r0 - 32);
                int v3 = ((int)acc[3][j] & (int)0xFFFFE000) | (r0 - 48);
                int hi = imax(imax(v0, v1), imax(v2, v3));
                int m  = imin(bq1[j], hi);
                bq1[j] = imax(bq1[j], hi);
                bq2[j] = imax(bq2[j], m);
            }
        }
        __syncthreads();
    }

    // butterfly top-2 merge across 16-lane code groups
#pragma unroll
    for (int off = 1; off < 16; off <<= 1) {
#pragma unroll
        for (int j = 0; j < 4; j++) {
            int o1 = __shfl_xor(bq1[j], off, 64);
            int o2 = __shfl_xor(bq2[j], off, 64);
            int m  = imin(bq1[j], o1);
            bq1[j] = imax(bq1[j], o1);
            bq2[j] = imax(imax(bq2[j], o2), m);
        }
    }
    if ((lane & 15) == 0) {
        int rowbase = blockIdx.x * PIX + w * 16 + (lane >> 4) * 4;
#pragma unroll
        for (int j = 0; j < 4; j++)
            pk2[(size_t)chunk * N_ + rowbase + j] = make_int2(bq1[j], bq2[j]);
    }
}

// exact rescore of one candidate code against z[32]
__device__ __forceinline__ float rescore(const float* __restrict__ emb, int k,
                                         const float* zrow) {
    const float4* r = (const float4*)(emb + (size_t)k * E_);
    float4 v[8];
    float ss = 0.f;
#pragma unroll
    for (int i = 0; i < 8; i++) {
        v[i] = r[i];
        ss += v[i].x * v[i].x + v[i].y * v[i].y + v[i].z * v[i].z + v[i].w * v[i].w;
    }
    float inv = 1.0f / fmaxf(sqrtf(ss), 1e-12f);
    const float4* zp = (const float4*)zrow;
    float sx = 0.f, sy = 0.f, sz = 0.f, sw = 0.f;
#pragma unroll
    for (int i = 0; i < 8; i++) {
        float4 e4 = make_float4(v[i].x * inv, v[i].y * inv, v[i].z * inv, v[i].w * inv);
        float4 zr = zp[i];
        sx += zr.x * e4.x; sy += zr.y * e4.y;
        sz += zr.z * e4.z; sw += zr.w * e4.w;
    }
    return (sx + sy) + (sz + sw);
}

// ---------------- K2: rescore 16 candidates (2/thread), gather + zq/idx/qloss-partial ----------------
// 1024 blocks, 256 thr, 32 pixels/block, 8 thr/pixel: thread c8 rescores chunk c8's (top1, top2).
__global__ __launch_bounds__(256) void k_scatter(const float* __restrict__ zws,
                                                 const int2* __restrict__ pk2,
                                                 const float* __restrict__ emb,
                                                 float* __restrict__ out_zq,
                                                 float* __restrict__ out_idx,
                                                 float* __restrict__ qpart) {
    __shared__ float zbuf[32 * E_];    // 4 KB
    __shared__ int   idxs_s[32];
    __shared__ float red[4];
    int tid = threadIdx.x;

    // coalesced z load: 1024 floats = 256 float4
    const float4* zsrc = (const float4*)(zws + (size_t)blockIdx.x * 32 * E_);
    ((float4*)zbuf)[tid] = zsrc[tid];
    __syncthreads();

    {   // 16 candidates per pixel: (chunk 0..7) x (top1, top2)
        int p = tid >> 3, c8 = tid & 7;
        int nn = blockIdx.x * 32 + p;
        int2 c2 = pk2[(size_t)c8 * N_ + nn];
        u64 pkd = 0;
#pragma unroll
        for (int t = 0; t < 2; t++) {
            int raw = t ? c2.y : c2.x;
            int k = 8191 - (raw & 0x1fff);
            k = k < 0 ? 0 : (k > K_ - 1 ? K_ - 1 : k);
            float s = rescore(emb, k, zbuf + p * E_);
            u64 pk = ((u64)ford(s) << 32) | (unsigned)(K_ - 1 - k);  // ties -> lowest idx
            pkd = pkd > pk ? pkd : pk;
        }
        u64 o = __shfl_xor(pkd, 1, 64); pkd = pkd > o ? pkd : o;
        o = __shfl_xor(pkd, 2, 64);     pkd = pkd > o ? pkd : o;
        o = __shfl_xor(pkd, 4, 64);     pkd = pkd > o ? pkd : o;
        if (c8 == 0) {
            int bi = K_ - 1 - (int)(unsigned)(pkd & 0xffffffffu);
            idxs_s[p] = bi;
            out_idx[nn] = (float)bi;
        }
    }
    __syncthreads();

    int lp = tid & 31, eg = tid >> 5;     // eg 0..7, 4 e's each
    int n  = blockIdx.x * 32 + lp;        // 32 | 4096: no image crossing
    int b  = n >> 12, hw = n & (HW_ - 1);
    int idx = idxs_s[lp];
    float4 e4 = *(const float4*)(emb + (size_t)idx * E_ + eg * 4);
    float* o = out_zq + (size_t)b * E_ * HW_ + (size_t)(eg * 4) * HW_ + hw;

    float z0 = zbuf[lp * E_ + eg * 4 + 0];
    float z1 = zbuf[lp * E_ + eg * 4 + 1];
    float z2 = zbuf[lp * E_ + eg * 4 + 2];
    float z3 = zbuf[lp * E_ + eg * 4 + 3];
    o[0]                 = e4.x;
    o[(size_t)1 * HW_]   = e4.y;
    o[(size_t)2 * HW_]   = e4.z;
    o[(size_t)3 * HW_]   = e4.w;
    float d0 = e4.x - z0, d1 = e4.y - z1, d2 = e4.z - z2, d3 = e4.w - z3;
    float sq = d0*d0 + d1*d1 + d2*d2 + d3*d3;

#pragma unroll
    for (int off = 32; off > 0; off >>= 1) sq += __shfl_down(sq, off);
    int lane = tid & 63, wid = tid >> 6;
    if (lane == 0) red[wid] = sq;
    __syncthreads();
    if (tid == 0) qpart[blockIdx.x] = red[0] + red[1] + red[2] + red[3];
}

// ---------------- K3: segment-sum + full EMA/division/qloss epilogue ----------------
// grid K/KSEG = 512 blocks (2/CU); block owns codes [kbase, kbase+KSEG).
// Tile-list compaction (verified): scan 8 px/thread coalesced, LDS match list,
// fully-parallel list processing (8 rows x 32 e in flight).
__global__ __launch_bounds__(256) void k_dwfinal(const float* __restrict__ zws,
                                                 const float* __restrict__ idxf,
                                                 const float* __restrict__ cs,
                                                 const float* __restrict__ ew,
                                                 const float* __restrict__ part_cs,
                                                 const float* __restrict__ qpart,
                                                 float* __restrict__ out_nw,
                                                 float* __restrict__ out_nemb,
                                                 float* __restrict__ out_ncs,
                                                 float* __restrict__ out_ql) {
    __shared__ float acc[KSEG * E_];   // 2 KB
    __shared__ int   cnt_s[KSEG];
    __shared__ int   plist[2048];      // worst-case one tile fully matching
    __shared__ int   lcnt;
    __shared__ float nsum_s;
    int tid = threadIdx.x;
    int kbase = blockIdx.x * KSEG;

#pragma unroll
    for (int i = 0; i < KSEG * E_ / 256; i++) acc[tid + i * 256] = 0.f;
    if (tid < KSEG) cnt_s[tid] = 0;
    if (tid == 0) lcnt = 0;
    __syncthreads();

    const float4* idx4 = (const float4*)idxf;
    for (int tile = 0; tile < N_ / 2048; ++tile) {   // 16 tiles
        int pbase = tile * 2048 + tid * 8;
        float4 f0 = idx4[tile * 512 + tid * 2];
        float4 f1 = idx4[tile * 512 + tid * 2 + 1];
        float fs[8] = {f0.x, f0.y, f0.z, f0.w, f1.x, f1.y, f1.z, f1.w};
#pragma unroll
        for (int s = 0; s < 8; s++) {
            unsigned d = (unsigned)((int)fs[s] - kbase);
            if (d < (unsigned)KSEG) {
                int pos = atomicAdd(&lcnt, 1);
                plist[pos] = ((pbase + s) << 5) | (int)d;
                atomicAdd(cnt_s + (int)d, 1);
            }
        }
        __syncthreads();
        int cnt = lcnt;
        int e = tid & 31;
        for (int m = tid >> 5; m < cnt; m += 8) {
            int pk = plist[m];
            int nn = pk >> 5;
            float zv = zws[(size_t)nn * E_ + e];        // 128B coalesced per match
            atomicAdd(acc + (pk & 31) * E_ + e, zv);    // banks 0..31, conflict-free
        }
        __syncthreads();
        if (tid == 0) lcnt = 0;
        __syncthreads();
    }

    // nsum = DECAY*sum(cs_in) + OMD*N   (sum(counts) == N exactly)
    if (tid < 64) {                      // whole wave 0 active: shfl sources valid
        float s = (tid < 16) ? part_cs[tid] : 0.f;
        s += __shfl_down(s, 8);
        s += __shfl_down(s, 4);
        s += __shfl_down(s, 2);
        s += __shfl_down(s, 1);
        if (tid == 0) nsum_s = DECAY_ * s + OMD_ * (float)N_;
    }
    __syncthreads();
    float nsum = nsum_s;

#pragma unroll
    for (int i = 0; i < KSEG * E_ / 256; i++) {
        int local = tid + i * 256;        // 0..511
        int kl = local >> 5, c = local & 31;
        int k = kbase + kl;
        float v = DECAY_ * ew[(size_t)k * E_ + c] + OMD_ * acc[local];
        out_nw[(size_t)k * E_ + c] = v;
        float csk = DECAY_ * cs[k] + OMD_ * (float)cnt_s[kl];
        float denom = (csk + EPS_) / (nsum + (float)K_ * EPS_) * nsum;
        out_nemb[(size_t)k * E_ + c] = v / denom;
        if (c == 0) out_ncs[k] = csk;
    }

    if (blockIdx.x == 0 && tid < 64) {
        float s = 0.f;
#pragma unroll
        for (int i = 0; i < 16; i++) s += qpart[tid + i * 64];   // 1024 partials
#pragma unroll
        for (int off = 32; off > 0; off >>= 1) s += __shfl_down(s, off);
        if (tid == 0) out_ql[0] = BETA_ * s / (float)(B_ * E_ * HW_);
    }
}

extern "C" void kernel_launch(void* const* d_in, const int* in_sizes, int n_in,
                              void* d_out, int out_size, void* d_ws, size_t ws_size,
                              hipStream_t stream) {
    const float* x   = (const float*)d_in[0];
    const float* Wq  = (const float*)d_in[1];
    const float* bq  = (const float*)d_in[2];
    const float* emb = (const float*)d_in[3];
    const float* cs  = (const float*)d_in[4];
    const float* ew  = (const float*)d_in[5];
    float* out = (float*)d_out;
    float* ws  = (float*)d_ws;

    // 4 dispatches total; no memset (all ws words written before read).
    k_pre<<<16 + N_ / 64, 512, 0, stream>>>(emb, cs,
        (uint4*)(ws + WS_EH), (uint4*)(ws + WS_EM), ws + WS_PCS,
        x, Wq, bq, ws + WS_Z);
    k_score_mfma<<<dim3(N_ / PIX, NCHUNK), 512, 0, stream>>>(ws + WS_Z,
        (const char*)(ws + WS_EH), (const char*)(ws + WS_EM),
        (int2*)(ws + WS_PACK));
    k_scatter<<<N_ / 32, 256, 0, stream>>>(ws + WS_Z,
        (const int2*)(ws + WS_PACK), emb,
        out + O_ZQ, out + O_IDX, ws + WS_QP);
    k_dwfinal<<<K_ / KSEG, 256, 0, stream>>>(ws + WS_Z, out + O_IDX, cs, ew,
                                             ws + WS_PCS, ws + WS_QP,
                                             out + O_NW, out + O_NEMB,
                                             out + O_NCS, out + O_QL);
}

// Round 12
// 188.116 us; speedup vs baseline: 1.1145x; 1.0177x over previous
//
#include <hip/hip_runtime.h>

#define B_ 8
#define C_ 256
#define HW_ 4096
#define E_ 32
#define K_ 8192
#define N_ 32768          // B*H*W
#define NCHUNK 8
#define KC_ (K_ / NCHUNK) // 1024
#define NSTAGE (KC_ / 128)   // 8
#define KSEG 16              // codes per k_dwfinal block
#define PIX 256              // pixels per k_score block (2 sets of 16 per wave)

#define DECAY_ 0.99f
#define OMD_   0.01f
#define EPS_   1e-5f
#define BETA_  0.25f

// ---- output layout (fp32 elements, concatenated in reference return order) ----
#define O_ZQ   0          // [B,E,H,W] 1048576
#define O_IDX  1048576    // [B,H,W]   32768
#define O_QL   1081344    // scalar    1
#define O_NEMB 1081345    // [K,E]     262144
#define O_NCS  1343489    // [K]       8192
#define O_NW   1351681    // [K,E]     262144

// ---- workspace layout (float offsets); high-water 1836048 floats = 7.3 MB ----
// eh/em PRE-SWIZZLED to MFMA-frag order: uint4 chunk (tile t, quad q, c15) at t*64+q*16+c15.
#define WS_EH   0u        // K*E bf16 hi   [0,       131072)
#define WS_EM   131072u   // K*E bf16 lo   [131072,  262144)
#define WS_Z    262144u   // N*E fp32 z    [262144, 1310720)
#define WS_PACK 1310720u  // 8 chunks x N int2 (top1,top2) [1310720, 1835008)
#define WS_PCS  1835008u  // 16 per-block partial sums of cs_in
#define WS_QP   1835024u  // 1024 per-block qloss partials
// NO memset needed: every ws word consumed is written first by a prior kernel.

typedef float f32x4 __attribute__((ext_vector_type(4)));
typedef short s16x8 __attribute__((ext_vector_type(8)));
typedef unsigned long long u64;

__device__ __forceinline__ unsigned short f2bf(float f) {
    unsigned u = __float_as_uint(f);
    u = u + 0x7fffu + ((u >> 16) & 1u);
    return (unsigned short)(u >> 16);
}
__device__ __forceinline__ float bf2f(unsigned short h) {
    return __uint_as_float(((unsigned)h) << 16);
}
__device__ __forceinline__ unsigned ford(float f) {
    unsigned u = __float_as_uint(f);
    return (u & 0x80000000u) ? ~u : (u | 0x80000000u);
}
__device__ __forceinline__ int imax(int a, int b) { return a > b ? a : b; }
__device__ __forceinline__ int imin(int a, int b) { return a < b ? a : b; }

__device__ __forceinline__ void gload_lds16(const void* g, void* l) {
    __builtin_amdgcn_global_load_lds(
        (const __attribute__((address_space(1))) unsigned int*)g,
        (__attribute__((address_space(3))) unsigned int*)l, 16, 0, 0);
}

// ---------------- K0: fused {norm_split + cs-partials} || {z = x@WqT + bq}, 512 thr ----------------
// blocks [0,16): codebook normalize/split, 1 row/thread + cs partial.
// blocks [16,528): z for 64 pixels each (1 px x 4 e per thread) -> 2+ blocks/CU.
__global__ __launch_bounds__(512) void k_pre(const float* __restrict__ emb,
                                             const float* __restrict__ cs,
                                             uint4* __restrict__ eh16,
                                             uint4* __restrict__ em16,
                                             float* __restrict__ part_cs,
                                             const float* __restrict__ x,
                                             const float* __restrict__ Wq,
                                             const float* __restrict__ bq,
                                             float* __restrict__ zout) {
    __shared__ float wqt[C_ * E_];   // 32 KB (z branch)
    __shared__ float red8[8];        // (norm branch cs reduce)
    int tid = threadIdx.x;

    if (blockIdx.x < 16) {
        // ---- norm_split branch: one full row per thread ----
        int k = blockIdx.x * 512 + tid;            // 0..8191
        const float4* r = (const float4*)(emb + (size_t)k * E_);
        float v[E_];
        float ss = 0.f;
#pragma unroll
        for (int i = 0; i < 8; i++) {
            float4 t = r[i];
            v[i*4+0] = t.x; v[i*4+1] = t.y; v[i*4+2] = t.z; v[i*4+3] = t.w;
            ss += t.x*t.x + t.y*t.y + t.z*t.z + t.w*t.w;
        }
        float inv = 1.0f / fmaxf(sqrtf(ss), 1e-12f);
        unsigned short h1a[E_], h2a[E_];
#pragma unroll
        for (int e = 0; e < E_; e++) {
            float en = v[e] * inv;
            unsigned short h1 = f2bf(en);
            float r1 = en - bf2f(h1);
            h1a[e] = h1; h2a[e] = f2bf(r1);
        }
        int t = k >> 4, c15 = k & 15;
#pragma unroll
        for (int i = 0; i < 4; i++) {   // quad i = elements 8i..8i+7
            eh16[t * 64 + i * 16 + c15] = ((uint4*)h1a)[i];
            em16[t * 64 + i * 16 + c15] = ((uint4*)h2a)[i];
        }

        // per-block partial of sum(cs_in): rows [blockIdx*512, +512)
        float cv = cs[blockIdx.x * 512 + tid];
#pragma unroll
        for (int off = 32; off > 0; off >>= 1) cv += __shfl_down(cv, off);
        int lane = tid & 63, wid = tid >> 6;
        if (lane == 0) red8[wid] = cv;
        __syncthreads();
        if (tid == 0) {
            float s = 0.f;
#pragma unroll
            for (int i = 0; i < 8; i++) s += red8[i];
            part_cs[blockIdx.x] = s;
        }
        return;
    }

    // ---- z branch: 64 pixels; thread owns 1 px x 4 e's ----
    int zb = blockIdx.x - 16;
#pragma unroll
    for (int i = 0; i < 16; i++) {
        int g = i * 512 + tid;        // g = e*256 + c  (Wq is [E,C])
        int e = g >> 8;
        int c = g & 255;
        wqt[c * E_ + e] = Wq[g];
    }
    __syncthreads();
    int lp = tid & 63, eg = tid >> 6;   // eg 0..7, 4 e's each
    int n0 = zb * 64 + lp;
    int b  = n0 >> 12, hw = n0 & (HW_ - 1);
    const float* xp = x + (size_t)b * C_ * HW_ + hw;
    float a0 = 0.f, a1 = 0.f, a2 = 0.f, a3 = 0.f;
#pragma unroll 8
    for (int c = 0; c < C_; c++) {
        float xv = xp[(size_t)c * HW_];
        float4 wv = *(const float4*)(wqt + c * E_ + eg * 4);   // wave-uniform broadcast
        a0 += xv * wv.x; a1 += xv * wv.y; a2 += xv * wv.z; a3 += xv * wv.w;
    }
    *(float4*)(zout + (size_t)n0 * E_ + eg * 4) =
        make_float4(a0 + bq[eg*4+0], a1 + bq[eg*4+1],
                    a2 + bq[eg*4+2], a3 + bq[eg*4+3]);
}

// ---------------- K1: MFMA score + int-packed per-pixel chunk-local top-2 ----------------
// grid (N/256, NCHUNK=8) = 1024 blocks, 512 thr (8 waves), 256 pixels, 1/8 codebook per block.
// TWO A-fragment sets per wave (32 px/wave): each ds_read_b128 B-fragment feeds both sets,
// halving per-pixel LDS traffic (round-11 analysis: LDS read pipe ~41 us was the largest
// consumer). Set-B MFMAs overlap set-A selection VALU.
// NO min-waves clause (round-3: forcing occupancy spills; WRITE_SIZE is the tripwire).
// LDS: [0,16384) buf0, [16384,32768) buf1 (stage: 8KB hi + 8KB lo).
__global__ __launch_bounds__(512) void k_score_mfma(const float* __restrict__ zws,
                                                    const char* __restrict__ ehb,
                                                    const char* __restrict__ emb_b,
                                                    int2* __restrict__ pk2) {
    __shared__ __align__(16) char smem[32768];

    int tid  = threadIdx.x;
    int lane = tid & 63;
    int w    = tid >> 6;          // 0..7
    int chunk = blockIdx.y;

    // ---- A fragments from cached z: z * 2^27 (exact), 2-way bf16 split.
    //      A[m=lane&15][k=(lane>>4)*8+j]; set A = px w*32+(lane&15), set B = +16. ----
    s16x8 a1A, a2A, a1B, a2B;
    {
        int plocA = w * 32 + (lane & 15);         // 0..255
        int e0    = (lane >> 4) * 8;
#pragma unroll
        for (int s = 0; s < 2; s++) {
            int n0 = blockIdx.x * PIX + plocA + s * 16;
            const float4* zp = (const float4*)(zws + (size_t)n0 * E_ + e0);
            float4 z0 = zp[0], z1 = zp[1];
            float zz[8] = {z0.x, z0.y, z0.z, z0.w, z1.x, z1.y, z1.z, z1.w};
            s16x8 h1v, h2v;
#pragma unroll
            for (int j = 0; j < 8; j++) {
                float zv = zz[j] * 134217728.0f;  // 2^27
                unsigned short h1 = f2bf(zv);
                float r1 = zv - bf2f(h1);
                h1v[j] = (short)h1; h2v[j] = (short)f2bf(r1);
            }
            if (s == 0) { a1A = h1v; a2A = h2v; }
            else        { a1B = h1v; a2B = h2v; }
        }
    }

    // staging sources (pre-swizzled planes are stage-linear); 512 thr x 2 = 1024 chunks
    const char* srcp[2];
#pragma unroll
    for (int i = 0; i < 2; i++) {
        int d = i * 512 + tid;
        int pl = d >> 9, dd = d & 511;
        srcp[i] = (pl ? emb_b : ehb) + (size_t)chunk * (KC_ * 64) + dd * 16;
    }

    // prologue: stage 0 -> buf0
#pragma unroll
    for (int i = 0; i < 2; i++)
        gload_lds16(srcp[i], smem + (i * 512 + tid) * 16);
    __syncthreads();

    int rbase = 8191 - chunk * KC_ - (lane & 15);
    int bqA1[4], bqA2[4], bqB1[4], bqB2[4];
#pragma unroll
    for (int j = 0; j < 4; j++) {
        bqA1[j] = (int)0x80000000; bqA2[j] = (int)0x80000000;
        bqB1[j] = (int)0x80000000; bqB2[j] = (int)0x80000000;
    }
    f32x4 zero4 = {0.f, 0.f, 0.f, 0.f};

    for (int st = 0; st < NSTAGE; st++) {
        if (st + 1 < NSTAGE) {
            char* dst = smem + ((st + 1) & 1) * 16384;
#pragma unroll
            for (int i = 0; i < 2; i++)
                gload_lds16(srcp[i] + (size_t)(st + 1) * 8192, dst + (i * 512 + tid) * 16);
        }
        const char* cur = smem + (st & 1) * 16384;
        int rst = rbase - st * 128;

#pragma unroll
        for (int g = 0; g < 2; g++) {
            int ct = g * 4;
            s16x8 b1[4], b2[4];
#pragma unroll
            for (int q = 0; q < 4; q++) {
                b1[q] = ((const s16x8*)(cur +        (ct + q) * 1024))[lane];
                b2[q] = ((const s16x8*)(cur + 8192 + (ct + q) * 1024))[lane];
            }
            int r0 = rst - ct * 16;
            // ---- set A: 12 MFMA + select ----
            {
                f32x4 acc[4];
#pragma unroll
                for (int q = 0; q < 4; q++)
                    acc[q] = __builtin_amdgcn_mfma_f32_16x16x32_bf16(a1A, b1[q], zero4, 0, 0, 0);
#pragma unroll
                for (int q = 0; q < 4; q++)
                    acc[q] = __builtin_amdgcn_mfma_f32_16x16x32_bf16(a1A, b2[q], acc[q], 0, 0, 0);
#pragma unroll
                for (int q = 0; q < 4; q++)
                    acc[q] = __builtin_amdgcn_mfma_f32_16x16x32_bf16(a2A, b1[q], acc[q], 0, 0, 0);
                // tournament over 4 tiles; group winner -> running top-2 (safe: packed-key
                // tie P ~ 1e-4/run; exact rescore of 16 candidates covers ties).
#pragma unroll
                for (int j = 0; j < 4; j++) {
                    int v0 = ((int)acc[0][j] & (int)0xFFFFE000) | r0;
                    int v1 = ((int)acc[1][j] & (int)0xFFFFE000) | (r0 - 16);
                    int v2 = ((int)acc[2][j] & (int)0xFFFFE000) | (r0 - 32);
                    int v3 = ((int)acc[3][j] & (int)0xFFFFE000) | (r0 - 48);
                    int hi = imax(imax(v0, v1), imax(v2, v3));
                    int m  = imin(bqA1[j], hi);
                    bqA1[j] = imax(bqA1[j], hi);
                    bqA2[j] = imax(bqA2[j], m);
                }
            }
            // ---- set B: reuse b1/b2 registers (no extra LDS reads) ----
            {
                f32x4 acc[4];
#pragma unroll
                for (int q = 0; q < 4; q++)
                    acc[q] = __builtin_amdgcn_mfma_f32_16x16x32_bf16(a1B, b1[q], zero4, 0, 0, 0);
#pragma unroll
                for (int q = 0; q < 4; q++)
                    acc[q] = __builtin_amdgcn_mfma_f32_16x16x32_bf16(a1B, b2[q], acc[q], 0, 0, 0);
#pragma unroll
                for (int q = 0; q < 4; q++)
                    acc[q] = __builtin_amdgcn_mfma_f32_16x16x32_bf16(a2B, b1[q], acc[q], 0, 0, 0);
#pragma unroll
                for (int j = 0; j < 4; j++) {
                    int v0 = ((int)acc[0][j] & (int)0xFFFFE000) | r0;
                    int v1 = ((int)acc[1][j] & (int)0xFFFFE000) | (r0 - 16);
                    int v2 = ((int)acc[2][j] & (int)0xFFFFE000) | (r0 - 32);
                    int v3 = ((int)acc[3][j] & (int)0xFFFFE000) | (r0 - 48);
                    int hi = imax(imax(v0, v1), imax(v2, v3));
                    int m  = imin(bqB1[j], hi);
                    bqB1[j] = imax(bqB1[j], hi);
                    bqB2[j] = imax(bqB2[j], m);
                }
            }
        }
        __syncthreads();
    }

    // butterfly top-2 merge across 16-lane code groups, both sets
#pragma unroll
    for (int off = 1; off < 16; off <<= 1) {
#pragma unroll
        for (int j = 0; j < 4; j++) {
            int o1 = __shfl_xor(bqA1[j], off, 64);
            int o2 = __shfl_xor(bqA2[j], off, 64);
            int m  = imin(bqA1[j], o1);
            bqA1[j] = imax(bqA1[j], o1);
            bqA2[j] = imax(imax(bqA2[j], o2), m);
            int p1 = __shfl_xor(bqB1[j], off, 64);
            int p2 = __shfl_xor(bqB2[j], off, 64);
            int n  = imin(bqB1[j], p1);
            bqB1[j] = imax(bqB1[j], p1);
            bqB2[j] = imax(imax(bqB2[j], p2), n);
        }
    }
    if ((lane & 15) == 0) {
        int rowbase = blockIdx.x * PIX + w * 32 + (lane >> 4) * 4;
#pragma unroll
        for (int j = 0; j < 4; j++) {
            pk2[(size_t)chunk * N_ + rowbase + j]      = make_int2(bqA1[j], bqA2[j]);
            pk2[(size_t)chunk * N_ + rowbase + 16 + j] = make_int2(bqB1[j], bqB2[j]);
        }
    }
}

// exact rescore of one candidate code against z[32]
__device__ __forceinline__ float rescore(const float* __restrict__ emb, int k,
                                         const float* zrow) {
    const float4* r = (const float4*)(emb + (size_t)k * E_);
    float4 v[8];
    float ss = 0.f;
#pragma unroll
    for (int i = 0; i < 8; i++) {
        v[i] = r[i];
        ss += v[i].x * v[i].x + v[i].y * v[i].y + v[i].z * v[i].z + v[i].w * v[i].w;
    }
    float inv = 1.0f / fmaxf(sqrtf(ss), 1e-12f);
    const float4* zp = (const float4*)zrow;
    float sx = 0.f, sy = 0.f, sz = 0.f, sw = 0.f;
#pragma unroll
    for (int i = 0; i < 8; i++) {
        float4 e4 = make_float4(v[i].x * inv, v[i].y * inv, v[i].z * inv, v[i].w * inv);
        float4 zr = zp[i];
        sx += zr.x * e4.x; sy += zr.y * e4.y;
        sz += zr.z * e4.z; sw += zr.w * e4.w;
    }
    return (sx + sy) + (sz + sw);
}

// ---------------- K2: rescore 16 candidates (2/thread), gather + zq/idx/qloss-partial ----------------
// 1024 blocks, 256 thr, 32 pixels/block, 8 thr/pixel: thread c8 rescores chunk c8's (top1, top2).
__global__ __launch_bounds__(256) void k_scatter(const float* __restrict__ zws,
                                                 const int2* __restrict__ pk2,
                                                 const float* __restrict__ emb,
                                                 float* __restrict__ out_zq,
                                                 float* __restrict__ out_idx,
                                                 float* __restrict__ qpart) {
    __shared__ float zbuf[32 * E_];    // 4 KB
    __shared__ int   idxs_s[32];
    __shared__ float red[4];
    int tid = threadIdx.x;

    // coalesced z load: 1024 floats = 256 float4
    const float4* zsrc = (const float4*)(zws + (size_t)blockIdx.x * 32 * E_);
    ((float4*)zbuf)[tid] = zsrc[tid];
    __syncthreads();

    {   // 16 candidates per pixel: (chunk 0..7) x (top1, top2)
        int p = tid >> 3, c8 = tid & 7;
        int nn = blockIdx.x * 32 + p;
        int2 c2 = pk2[(size_t)c8 * N_ + nn];
        u64 pkd = 0;
#pragma unroll
        for (int t = 0; t < 2; t++) {
            int raw = t ? c2.y : c2.x;
            int k = 8191 - (raw & 0x1fff);
            k = k < 0 ? 0 : (k > K_ - 1 ? K_ - 1 : k);
            float s = rescore(emb, k, zbuf + p * E_);
            u64 pk = ((u64)ford(s) << 32) | (unsigned)(K_ - 1 - k);  // ties -> lowest idx
            pkd = pkd > pk ? pkd : pk;
        }
        u64 o = __shfl_xor(pkd, 1, 64); pkd = pkd > o ? pkd : o;
        o = __shfl_xor(pkd, 2, 64);     pkd = pkd > o ? pkd : o;
        o = __shfl_xor(pkd, 4, 64);     pkd = pkd > o ? pkd : o;
        if (c8 == 0) {
            int bi = K_ - 1 - (int)(unsigned)(pkd & 0xffffffffu);
            idxs_s[p] = bi;
            out_idx[nn] = (float)bi;
        }
    }
    __syncthreads();

    int lp = tid & 31, eg = tid >> 5;     // eg 0..7, 4 e's each
    int n  = blockIdx.x * 32 + lp;        // 32 | 4096: no image crossing
    int b  = n >> 12, hw = n & (HW_ - 1);
    int idx = idxs_s[lp];
    float4 e4 = *(const float4*)(emb + (size_t)idx * E_ + eg * 4);
    float* o = out_zq + (size_t)b * E_ * HW_ + (size_t)(eg * 4) * HW_ + hw;

    float z0 = zbuf[lp * E_ + eg * 4 + 0];
    float z1 = zbuf[lp * E_ + eg * 4 + 1];
    float z2 = zbuf[lp * E_ + eg * 4 + 2];
    float z3 = zbuf[lp * E_ + eg * 4 + 3];
    o[0]                 = e4.x;
    o[(size_t)1 * HW_]   = e4.y;
    o[(size_t)2 * HW_]   = e4.z;
    o[(size_t)3 * HW_]   = e4.w;
    float d0 = e4.x - z0, d1 = e4.y - z1, d2 = e4.z - z2, d3 = e4.w - z3;
    float sq = d0*d0 + d1*d1 + d2*d2 + d3*d3;

#pragma unroll
    for (int off = 32; off > 0; off >>= 1) sq += __shfl_down(sq, off);
    int lane = tid & 63, wid = tid >> 6;
    if (lane == 0) red[wid] = sq;
    __syncthreads();
    if (tid == 0) qpart[blockIdx.x] = red[0] + red[1] + red[2] + red[3];
}

// ---------------- K3: segment-sum + full EMA/division/qloss epilogue ----------------
// grid K/KSEG = 512 blocks (2/CU); block owns codes [kbase, kbase+KSEG).
// Tile-list compaction (verified): scan 8 px/thread coalesced, LDS match list,
// fully-parallel list processing (8 rows x 32 e in flight).
__global__ __launch_bounds__(256) void k_dwfinal(const float* __restrict__ zws,
                                                 const float* __restrict__ idxf,
                                                 const float* __restrict__ cs,
                                                 const float* __restrict__ ew,
                                                 const float* __restrict__ part_cs,
                                                 const float* __restrict__ qpart,
                                                 float* __restrict__ out_nw,
                                                 float* __restrict__ out_nemb,
                                                 float* __restrict__ out_ncs,
                                                 float* __restrict__ out_ql) {
    __shared__ float acc[KSEG * E_];   // 2 KB
    __shared__ int   cnt_s[KSEG];
    __shared__ int   plist[2048];      // worst-case one tile fully matching
    __shared__ int   lcnt;
    __shared__ float nsum_s;
    int tid = threadIdx.x;
    int kbase = blockIdx.x * KSEG;

#pragma unroll
    for (int i = 0; i < KSEG * E_ / 256; i++) acc[tid + i * 256] = 0.f;
    if (tid < KSEG) cnt_s[tid] = 0;
    if (tid == 0) lcnt = 0;
    __syncthreads();

    const float4* idx4 = (const float4*)idxf;
    for (int tile = 0; tile < N_ / 2048; ++tile) {   // 16 tiles
        int pbase = tile * 2048 + tid * 8;
        float4 f0 = idx4[tile * 512 + tid * 2];
        float4 f1 = idx4[tile * 512 + tid * 2 + 1];
        float fs[8] = {f0.x, f0.y, f0.z, f0.w, f1.x, f1.y, f1.z, f1.w};
#pragma unroll
        for (int s = 0; s < 8; s++) {
            unsigned d = (unsigned)((int)fs[s] - kbase);
            if (d < (unsigned)KSEG) {
                int pos = atomicAdd(&lcnt, 1);
                plist[pos] = ((pbase + s) << 5) | (int)d;
                atomicAdd(cnt_s + (int)d, 1);
            }
        }
        __syncthreads();
        int cnt = lcnt;
        int e = tid & 31;
        for (int m = tid >> 5; m < cnt; m += 8) {
            int pk = plist[m];
            int nn = pk >> 5;
            float zv = zws[(size_t)nn * E_ + e];        // 128B coalesced per match
            atomicAdd(acc + (pk & 31) * E_ + e, zv);    // banks 0..31, conflict-free
        }
        __syncthreads();
        if (tid == 0) lcnt = 0;
        __syncthreads();
    }

    // nsum = DECAY*sum(cs_in) + OMD*N   (sum(counts) == N exactly)
    if (tid < 64) {                      // whole wave 0 active: shfl sources valid
        float s = (tid < 16) ? part_cs[tid] : 0.f;
        s += __shfl_down(s, 8);
        s += __shfl_down(s, 4);
        s += __shfl_down(s, 2);
        s += __shfl_down(s, 1);
        if (tid == 0) nsum_s = DECAY_ * s + OMD_ * (float)N_;
    }
    __syncthreads();
    float nsum = nsum_s;

#pragma unroll
    for (int i = 0; i < KSEG * E_ / 256; i++) {
        int local = tid + i * 256;        // 0..511
        int kl = local >> 5, c = local & 31;
        int k = kbase + kl;
        float v = DECAY_ * ew[(size_t)k * E_ + c] + OMD_ * acc[local];
        out_nw[(size_t)k * E_ + c] = v;
        float csk = DECAY_ * cs[k] + OMD_ * (float)cnt_s[kl];
        float denom = (csk + EPS_) / (nsum + (float)K_ * EPS_) * nsum;
        out_nemb[(size_t)k * E_ + c] = v / denom;
        if (c == 0) out_ncs[k] = csk;
    }

    if (blockIdx.x == 0 && tid < 64) {
        float s = 0.f;
#pragma unroll
        for (int i = 0; i < 16; i++) s += qpart[tid + i * 64];   // 1024 partials
#pragma unroll
        for (int off = 32; off > 0; off >>= 1) s += __shfl_down(s, off);
        if (tid == 0) out_ql[0] = BETA_ * s / (float)(B_ * E_ * HW_);
    }
}

extern "C" void kernel_launch(void* const* d_in, const int* in_sizes, int n_in,
                              void* d_out, int out_size, void* d_ws, size_t ws_size,
                              hipStream_t stream) {
    const float* x   = (const float*)d_in[0];
    const float* Wq  = (const float*)d_in[1];
    const float* bq  = (const float*)d_in[2];
    const float* emb = (const float*)d_in[3];
    const float* cs  = (const float*)d_in[4];
    const float* ew  = (const float*)d_in[5];
    float* out = (float*)d_out;
    float* ws  = (float*)d_ws;

    // 4 dispatches total; no memset (all ws words written before read).
    k_pre<<<16 + N_ / 64, 512, 0, stream>>>(emb, cs,
        (uint4*)(ws + WS_EH), (uint4*)(ws + WS_EM), ws + WS_PCS,
        x, Wq, bq, ws + WS_Z);
    k_score_mfma<<<dim3(N_ / PIX, NCHUNK), 512, 0, stream>>>(ws + WS_Z,
        (const char*)(ws + WS_EH), (const char*)(ws + WS_EM),
        (int2*)(ws + WS_PACK));
    k_scatter<<<N_ / 32, 256, 0, stream>>>(ws + WS_Z,
        (const int2*)(ws + WS_PACK), emb,
        out + O_ZQ, out + O_IDX, ws + WS_QP);
    k_dwfinal<<<K_ / KSEG, 256, 0, stream>>>(ws + WS_Z, out + O_IDX, cs, ew,
                                             ws + WS_PCS, ws + WS_QP,
                                             out + O_NW, out + O_NEMB,
                                             out + O_NCS, out + O_QL);
}